// Round 2
// baseline (92.272 us; speedup 1.0000x reference)
//
#include <hip/hip_runtime.h>
#include <math.h>

constexpr int BLOCKS  = 1024;
constexpr int THREADS = 256;
constexpr int WAVES   = THREADS / 64;

__device__ __forceinline__ void score_accum(float4 p, float4 l,
                                            float& sc, float& sq) {
    const float cneg = -1.0f / 13.0f;
    const float cpos =  1.0f / 10.0f;
    float d0 = p.x - l.x, d1 = p.y - l.y, d2 = p.z - l.z, d3 = p.w - l.w;
    float t0 = d0 * (d0 < 0.0f ? cneg : cpos);
    float t1 = d1 * (d1 < 0.0f ? cneg : cpos);
    float t2 = d2 * (d2 < 0.0f ? cneg : cpos);
    float t3 = d3 * (d3 < 0.0f ? cneg : cpos);
    sc += (__expf(t0) - 1.0f) + (__expf(t1) - 1.0f)
        + (__expf(t2) - 1.0f) + (__expf(t3) - 1.0f);
    sq += d0 * d0 + d1 * d1 + d2 * d2 + d3 * d3;
}

__device__ __forceinline__ void block_reduce_store(float sc, float sq,
                                                   float* partials) {
    #pragma unroll
    for (int off = 32; off > 0; off >>= 1) {
        sc += __shfl_down(sc, off, 64);
        sq += __shfl_down(sq, off, 64);
    }
    __shared__ float s_sc[WAVES];
    __shared__ float s_sq[WAVES];
    const int lane = threadIdx.x & 63;
    const int wave = threadIdx.x >> 6;
    if (lane == 0) { s_sc[wave] = sc; s_sq[wave] = sq; }
    __syncthreads();
    if (threadIdx.x == 0) {
        float tsc = 0.0f, tsq = 0.0f;
        #pragma unroll
        for (int w = 0; w < WAVES; ++w) { tsc += s_sc[w]; tsq += s_sq[w]; }
        partials[blockIdx.x]          = tsc;
        partials[BLOCKS + blockIdx.x] = tsq;
    }
}

// Specialized: N == 8388608 -> exactly 8 float4 iters/thread, fully unrolled,
// all 16 loads issued before any compute (max memory-level parallelism).
template <int ITERS>
__global__ __launch_bounds__(THREADS)
void rul_partial_fixed(const float* __restrict__ pred,
                       const float* __restrict__ lab,
                       float* __restrict__ partials) {
    const float4* __restrict__ p4 = reinterpret_cast<const float4*>(pred);
    const float4* __restrict__ l4 = reinterpret_cast<const float4*>(lab);
    const int stride = BLOCKS * THREADS;
    const int base   = blockIdx.x * THREADS + threadIdx.x;

    float4 p[ITERS], l[ITERS];
    #pragma unroll
    for (int k = 0; k < ITERS; ++k) p[k] = p4[base + k * stride];
    #pragma unroll
    for (int k = 0; k < ITERS; ++k) l[k] = l4[base + k * stride];

    float sc = 0.0f, sq = 0.0f;
    #pragma unroll
    for (int k = 0; k < ITERS; ++k) score_accum(p[k], l[k], sc, sq);

    block_reduce_store(sc, sq, partials);
}

// Generic fallback (any n divisible by 4).
__global__ __launch_bounds__(THREADS)
void rul_partial_generic(const float* __restrict__ pred,
                         const float* __restrict__ lab,
                         float* __restrict__ partials, int n) {
    const float4* __restrict__ p4 = reinterpret_cast<const float4*>(pred);
    const float4* __restrict__ l4 = reinterpret_cast<const float4*>(lab);
    const int n4 = n >> 2;
    float sc = 0.0f, sq = 0.0f;
    for (int i = blockIdx.x * THREADS + threadIdx.x; i < n4;
         i += gridDim.x * THREADS) {
        score_accum(p4[i], l4[i], sc, sq);
    }
    block_reduce_store(sc, sq, partials);
}

__global__ __launch_bounds__(THREADS)
void rul_final(const float* __restrict__ partials,
               float* __restrict__ out, int n) {
    float sc = 0.0f, sq = 0.0f;
    for (int i = threadIdx.x; i < BLOCKS; i += THREADS) {
        sc += partials[i];
        sq += partials[BLOCKS + i];
    }
    #pragma unroll
    for (int off = 32; off > 0; off >>= 1) {
        sc += __shfl_down(sc, off, 64);
        sq += __shfl_down(sq, off, 64);
    }
    __shared__ float s_sc[WAVES];
    __shared__ float s_sq[WAVES];
    const int lane = threadIdx.x & 63;
    const int wave = threadIdx.x >> 6;
    if (lane == 0) { s_sc[wave] = sc; s_sq[wave] = sq; }
    __syncthreads();
    if (threadIdx.x == 0) {
        float tsc = 0.0f, tsq = 0.0f;
        #pragma unroll
        for (int w = 0; w < WAVES; ++w) { tsc += s_sc[w]; tsq += s_sq[w]; }
        out[0] = 0.5f * tsc + 0.5f * sqrtf(tsq / (float)n);
    }
}

extern "C" void kernel_launch(void* const* d_in, const int* in_sizes, int n_in,
                              void* d_out, int out_size, void* d_ws, size_t ws_size,
                              hipStream_t stream) {
    const float* pred = (const float*)d_in[0];
    const float* lab  = (const float*)d_in[1];
    const int n = in_sizes[0];
    float* partials = (float*)d_ws;  // 2*BLOCKS floats, fully overwritten

    if (n == BLOCKS * THREADS * 8 * 4) {
        rul_partial_fixed<8><<<BLOCKS, THREADS, 0, stream>>>(pred, lab, partials);
    } else {
        rul_partial_generic<<<BLOCKS, THREADS, 0, stream>>>(pred, lab, partials, n);
    }
    rul_final<<<1, THREADS, 0, stream>>>(partials, (float*)d_out, n);
}